// Round 18
// baseline (125.423 us; speedup 1.0000x reference)
//
#include <hip/hip_runtime.h>

typedef __attribute__((ext_vector_type(8))) short bf16x8;
typedef __attribute__((ext_vector_type(4))) float f32x4;

#define HWSZ 65536
#define WSW_OFF 0
#define ZP_OFF  131072
#define XT_OFF  262144

#define VMCNT(n) do { asm volatile("s_waitcnt vmcnt(" #n ")" ::: "memory"); \
                      __builtin_amdgcn_sched_barrier(0); } while (0)
#define BARRIER() do { __builtin_amdgcn_s_barrier(); \
                       __builtin_amdgcn_sched_barrier(0); } while (0)

__device__ inline unsigned to_bf16u(float f) {
    union { float f; unsigned u; } c; c.f = f;
    unsigned u = c.u;
    return (u + 0x7fffu + ((u >> 16) & 1u)) >> 16;   // round-nearest-even
}

// Weights fp32 [co][ci][9] -> bf16 swizzled wsw [chunk][kpos][co64][4 slot][8]; zero zpage
__global__ void wcvt(const float* __restrict__ wgt, char* __restrict__ ws) {
    if (blockIdx.x == 0 && threadIdx.x < 64)
        ((unsigned*)(ws + ZP_OFF))[threadIdx.x] = 0;
    unsigned short* wsw = (unsigned short*)(ws + WSW_OFF);
    int idx = blockIdx.x * 256 + threadIdx.x;       // 36864 total
    int co   = idx / 576;
    int rem  = idx - co * 576;
    int ci   = rem / 9;
    int kpos = rem - ci * 9;
    unsigned short v = (unsigned short)to_bf16u(wgt[idx]);
    int chunk = ci >> 5, cil = ci & 31;
    int slot = (cil >> 3) ^ (((co & 31) >> 1) & 3);
    wsw[((chunk * 9 + kpos) * 64 + co) * 32 + slot * 8 + (cil & 7)] = v;
}

// x fp32 NCHW -> bf16 channels-last xt[b][pix][octet-slot], column-swizzle baked in.
__global__ __launch_bounds__(256) void xcvt(const float* __restrict__ x, char* __restrict__ ws) {
    char* xt = ws + XT_OFF;
    const int tid = threadIdx.x;
    const int p4 = tid & 31, o = tid >> 5;
    const int pix0 = blockIdx.x * 128 + p4 * 4;
    const int b = blockIdx.y;
    const float* src = x + ((size_t)b * 64 + o * 8) * HWSZ + pix0;
    float4 v[8];
    #pragma unroll
    for (int k = 0; k < 8; ++k) v[k] = *(const float4*)(src + (size_t)k * HWSZ);
    #pragma unroll
    for (int j = 0; j < 4; ++j) {
        int pix = pix0 + j;
        int w = pix & 255;
        float e[8];
        e[0]=v[0].x; e[1]=v[1].x; e[2]=v[2].x; e[3]=v[3].x;
        e[4]=v[4].x; e[5]=v[5].x; e[6]=v[6].x; e[7]=v[7].x;
        if (j == 1) { e[0]=v[0].y; e[1]=v[1].y; e[2]=v[2].y; e[3]=v[3].y;
                      e[4]=v[4].y; e[5]=v[5].y; e[6]=v[6].y; e[7]=v[7].y; }
        if (j == 2) { e[0]=v[0].z; e[1]=v[1].z; e[2]=v[2].z; e[3]=v[3].z;
                      e[4]=v[4].z; e[5]=v[5].z; e[6]=v[6].z; e[7]=v[7].z; }
        if (j == 3) { e[0]=v[0].w; e[1]=v[1].w; e[2]=v[2].w; e[3]=v[3].w;
                      e[4]=v[4].w; e[5]=v[5].w; e[6]=v[6].w; e[7]=v[7].w; }
        unsigned u[4];
        #pragma unroll
        for (int k = 0; k < 4; ++k)
            u[k] = to_bf16u(e[2 * k]) | (to_bf16u(e[2 * k + 1]) << 16);
        int slot = o ^ (((w + 1) >> 1) & 3);   // XOR stays within o's chunk-half
        *(uint4*)(xt + (size_t)(b * HWSZ + pix) * 128 + slot * 16) = (uint4){u[0], u[1], u[2], u[3]};
    }
}

// Persistent conv: 256 blocks (1/CU), 8 tiles each, counted-vmcnt pipeline.
__global__ __launch_bounds__(256, 1) void maskconv_mfma(
    const char* __restrict__ ws, const int* __restrict__ mask,
    const float* __restrict__ bias, float* __restrict__ out)
{
    __shared__ unsigned short xs[2 * 384 * 32];   // 49152 B: chunk0 | chunk1 x-tiles
    __shared__ unsigned short wl[2 * 9 * 64 * 32];// 73728 B: all weights, loaded once

    const int tid  = threadIdx.x;
    const int lane = tid & 63;
    const int wv   = tid >> 6;          // wave 0..3
    const int coh  = wv >> 1;           // co-half
    const int rg   = wv & 1;            // row-group: rows rg*4..rg*4+3
    const int l15  = lane & 15;
    const int l4   = lane >> 4;
    const int pil  = lane >> 2;         // pixel-in-instruction 0..15
    const int slot = lane & 3;

    const int bk = blockIdx.x;          // 0..255
    char* xsb = (char*)xs;
    char* wlb = (char*)wl;

    // ---- stage x chunk for unit u: 6 glds/wave (incl. dummies), pure async ----
    auto stage_x = [&](int u, int chunk) {
        const int b  = u >> 8;
        const int tile = u & 255;
        const int tw = (tile & 7) * 32;
        const int th = (tile >> 3) * 8;
        #pragma unroll
        for (int q = 0; q < 6; ++q) {
            int i  = wv * 6 + q;        // 0..23
            int pi = i * 16 + pil;
            int r   = pi / 34;
            int lcv = pi - r * 34;
            int gr = th - 1 + r;
            int gc = tw - 1 + lcv;
            bool inb = (pi < 340) & ((unsigned)gr < 256u) & ((unsigned)gc < 256u);
            unsigned off = inb
                ? (unsigned)(XT_OFF + (unsigned)((b * HWSZ) + (gr << 8) + gc) * 128u + slot * 16)
                : (unsigned)(ZP_OFF + slot * 16);
            const char* g = ws + off + chunk * 64;
            unsigned short* l = xs + chunk * 12288 + i * 512;
            __builtin_amdgcn_global_load_lds(
                (const __attribute__((address_space(1))) void*)(const void*)g,
                (__attribute__((address_space(3))) void*)(void*)l, 16, 0, 0);
        }
    };

    // ---- full weight stage (once): 18 glds/wave ----
    auto stage_wl = [&]() {
        const unsigned short* base = (const unsigned short*)(ws + WSW_OFF);
        #pragma unroll
        for (int q = 0; q < 18; ++q) {
            int i = wv + 4 * q;         // 0..71
            const unsigned short* g = base + i * 512 + lane * 8;
            unsigned short* l = wl + i * 512;
            __builtin_amdgcn_global_load_lds(
                (const __attribute__((address_space(1))) void*)(const void*)g,
                (__attribute__((address_space(3))) void*)(void*)l, 16, 0, 0);
        }
    };

    f32x4 acc[8][2];

    auto do_mfma = [&](int chunk) {
        #pragma unroll
        for (int kh = 0; kh < 3; ++kh) {
            #pragma unroll
            for (int kw = 0; kw < 3; ++kw) {
                const int kpos = kh * 3 + kw;
                bf16x8 bfrag[2];
                #pragma unroll
                for (int j = 0; j < 2; ++j) {
                    int co = coh * 32 + j * 16 + l15;
                    int sl = l4 ^ (((co & 31) >> 1) & 3);
                    bfrag[j] = *(const bf16x8*)(wlb + chunk * 36864 + (kpos * 64 + co) * 64 + (sl << 4));
                }
                #pragma unroll
                for (int f = 0; f < 8; ++f) {
                    int fr = f >> 1, wh = f & 1;
                    int lc = wh * 16 + l15 + kw;
                    int r  = rg * 4 + fr + kh;
                    int s  = (lc >> 1) & 3;
                    bf16x8 afrag = *(const bf16x8*)(xsb + chunk * 24576 + (r * 34 + lc) * 64 + ((l4 ^ s) << 4));
                    #pragma unroll
                    for (int j = 0; j < 2; ++j)
                        acc[f][j] = __builtin_amdgcn_mfma_f32_16x16x32_bf16(
                            afrag, bfrag[j], acc[f][j], 0, 0, 0);
                }
            }
        }
    };

    // ---- prologue ----
    stage_wl();                 // 18 vm-ops
    stage_x(bk * 8, 0);         // 6 vm-ops

    float bv[2];
    #pragma unroll
    for (int j = 0; j < 2; ++j) bv[j] = bias[coh * 32 + j * 16 + l15];

    for (int it = 0; it < 8; ++it) {
        const int u  = bk * 8 + it;
        const int b  = u >> 8;
        const int tile = u & 255;
        const int tw = (tile & 7) * 32;
        const int th = (tile >> 3) * 8;

        #pragma unroll
        for (int f = 0; f < 8; ++f)
            #pragma unroll
            for (int j = 0; j < 2; ++j)
                acc[f][j] = (f32x4){0.f, 0.f, 0.f, 0.f};

        // ---- step A: issue mask (8) + stage chunk1 (6); wait chunk0 ready ----
        const int* mb = mask + (size_t)b * HWSZ;
        int4 mv[4][2];
        #pragma unroll
        for (int fr = 0; fr < 4; ++fr) {
            int h   = th + rg * 4 + fr;
            int wq0 = tw + l4 * 4;
            mv[fr][0] = *(const int4*)(mb + h * 256 + wq0);
            mv[fr][1] = *(const int4*)(mb + h * 256 + wq0 + 16);
        }
        stage_x(u, 1);
        VMCNT(14);              // leaves mask(8)+stage_c1(6): chunk0 + prior stores done
        BARRIER();
        do_mfma(0);
        BARRIER();

        // ---- step B: issue next tile's chunk0 (6); wait chunk1 + mask ready ----
        {
            int un = (u + 1 < 2048) ? (u + 1) : 0;
            stage_x(un, 0);
        }
        VMCNT(6);               // leaves stage_c0(next): chunk1 + mask done
        BARRIER();
        do_mfma(1);
        BARRIER();

        // ---- epilogue: bias + mask, 16 stores/wave ----
        #pragma unroll
        for (int fr = 0; fr < 4; ++fr) {
            int h   = th + rg * 4 + fr;
            int wq0 = tw + l4 * 4;
            float m00 = (float)mv[fr][0].x, m01 = (float)mv[fr][0].y;
            float m02 = (float)mv[fr][0].z, m03 = (float)mv[fr][0].w;
            float m10 = (float)mv[fr][1].x, m11 = (float)mv[fr][1].y;
            float m12 = (float)mv[fr][1].z, m13 = (float)mv[fr][1].w;
            #pragma unroll
            for (int j = 0; j < 2; ++j) {
                int co = coh * 32 + j * 16 + l15;
                float* obase = out + (((size_t)(b * 64 + co)) << 16) + h * 256;
                f32x4 a0 = acc[fr * 2 + 0][j];
                f32x4 a1 = acc[fr * 2 + 1][j];
                float4 o0, o1;
                o0.x = (a0.x + bv[j]) * m00;
                o0.y = (a0.y + bv[j]) * m01;
                o0.z = (a0.z + bv[j]) * m02;
                o0.w = (a0.w + bv[j]) * m03;
                o1.x = (a1.x + bv[j]) * m10;
                o1.y = (a1.y + bv[j]) * m11;
                o1.z = (a1.z + bv[j]) * m12;
                o1.w = (a1.w + bv[j]) * m13;
                *(float4*)(obase + wq0) = o0;
                *(float4*)(obase + wq0 + 16) = o1;
            }
        }
    }
}

extern "C" void kernel_launch(void* const* d_in, const int* in_sizes, int n_in,
                              void* d_out, int out_size, void* d_ws, size_t ws_size,
                              hipStream_t stream) {
    const float* x    = (const float*)d_in[0];
    const int*   mask = (const int*)d_in[1];
    const float* wgt  = (const float*)d_in[2];
    const float* bias = (const float*)d_in[3];
    float* out = (float*)d_out;
    char* ws = (char*)d_ws;     // uses XT_OFF + 64 MiB of ws

    wcvt<<<dim3(144), dim3(256), 0, stream>>>(wgt, ws);
    xcvt<<<dim3(512, 8), dim3(256), 0, stream>>>(x, ws);
    maskconv_mfma<<<dim3(256), dim3(256), 0, stream>>>(ws, mask, bias, out);
}

// Round 19
// 119.418 us; speedup vs baseline: 1.0503x; 1.0503x over previous
//
#include <hip/hip_runtime.h>

typedef __attribute__((ext_vector_type(8))) short bf16x8;
typedef __attribute__((ext_vector_type(4))) float f32x4;

#define HWSZ 65536
#define WSW_OFF 0
#define ZP_OFF  131072
#define XT_OFF  262144

#define VMCNT(n) do { asm volatile("s_waitcnt vmcnt(" #n ")" ::: "memory"); \
                      __builtin_amdgcn_sched_barrier(0); } while (0)
#define BARRIER() do { __builtin_amdgcn_s_barrier(); \
                       __builtin_amdgcn_sched_barrier(0); } while (0)

__device__ inline unsigned to_bf16u(float f) {
    union { float f; unsigned u; } c; c.f = f;
    unsigned u = c.u;
    return (u + 0x7fffu + ((u >> 16) & 1u)) >> 16;   // round-nearest-even
}

// Weights fp32 [co][ci][9] -> bf16 swizzled wsw [chunk][kpos][co64][4 slot][8]; zero zpage
__global__ void wcvt(const float* __restrict__ wgt, char* __restrict__ ws) {
    if (blockIdx.x == 0 && threadIdx.x < 64)
        ((unsigned*)(ws + ZP_OFF))[threadIdx.x] = 0;
    unsigned short* wsw = (unsigned short*)(ws + WSW_OFF);
    int idx = blockIdx.x * 256 + threadIdx.x;       // 36864 total
    int co   = idx / 576;
    int rem  = idx - co * 576;
    int ci   = rem / 9;
    int kpos = rem - ci * 9;
    unsigned short v = (unsigned short)to_bf16u(wgt[idx]);
    int chunk = ci >> 5, cil = ci & 31;
    int slot = (cil >> 3) ^ (((co & 31) >> 1) & 3);
    wsw[((chunk * 9 + kpos) * 64 + co) * 32 + slot * 8 + (cil & 7)] = v;
}

// x fp32 NCHW -> bf16 channels-last xt[b][pix][octet-slot], column-swizzle baked in.
__global__ __launch_bounds__(256) void xcvt(const float* __restrict__ x, char* __restrict__ ws) {
    char* xt = ws + XT_OFF;
    const int tid = threadIdx.x;
    const int p4 = tid & 31, o = tid >> 5;
    const int pix0 = blockIdx.x * 128 + p4 * 4;
    const int b = blockIdx.y;
    const float* src = x + ((size_t)b * 64 + o * 8) * HWSZ + pix0;
    float4 v[8];
    #pragma unroll
    for (int k = 0; k < 8; ++k) v[k] = *(const float4*)(src + (size_t)k * HWSZ);
    #pragma unroll
    for (int j = 0; j < 4; ++j) {
        int pix = pix0 + j;
        int w = pix & 255;
        float e[8];
        e[0]=v[0].x; e[1]=v[1].x; e[2]=v[2].x; e[3]=v[3].x;
        e[4]=v[4].x; e[5]=v[5].x; e[6]=v[6].x; e[7]=v[7].x;
        if (j == 1) { e[0]=v[0].y; e[1]=v[1].y; e[2]=v[2].y; e[3]=v[3].y;
                      e[4]=v[4].y; e[5]=v[5].y; e[6]=v[6].y; e[7]=v[7].y; }
        if (j == 2) { e[0]=v[0].z; e[1]=v[1].z; e[2]=v[2].z; e[3]=v[3].z;
                      e[4]=v[4].z; e[5]=v[5].z; e[6]=v[6].z; e[7]=v[7].z; }
        if (j == 3) { e[0]=v[0].w; e[1]=v[1].w; e[2]=v[2].w; e[3]=v[3].w;
                      e[4]=v[4].w; e[5]=v[5].w; e[6]=v[6].w; e[7]=v[7].w; }
        unsigned u[4];
        #pragma unroll
        for (int k = 0; k < 4; ++k)
            u[k] = to_bf16u(e[2 * k]) | (to_bf16u(e[2 * k + 1]) << 16);
        int slot = o ^ (((w + 1) >> 1) & 3);   // XOR stays within o's chunk-half
        *(uint4*)(xt + (size_t)(b * HWSZ + pix) * 128 + slot * 16) = (uint4){u[0], u[1], u[2], u[3]};
    }
}

// Persistent conv: 256 blocks (1/CU) x 512 threads (2 waves/SIMD), counted-vmcnt pipeline.
__global__ __launch_bounds__(512, 1) void maskconv_mfma(
    const char* __restrict__ ws, const int* __restrict__ mask,
    const float* __restrict__ bias, float* __restrict__ out)
{
    __shared__ unsigned short xs[2 * 384 * 32];   // 49152 B: chunk0 | chunk1 x-tiles
    __shared__ unsigned short wl[2 * 9 * 64 * 32];// 73728 B: all weights, loaded once

    const int tid  = threadIdx.x;
    const int lane = tid & 63;
    const int wv   = tid >> 6;          // wave 0..7
    const int coh  = wv >> 2;           // co-half
    const int rg   = wv & 3;            // row-group: rows rg*2..rg*2+1
    const int l15  = lane & 15;
    const int l4   = lane >> 4;
    const int pil  = lane >> 2;         // pixel-in-instruction 0..15
    const int slot = lane & 3;

    const int bk = blockIdx.x;          // 0..255
    char* xsb = (char*)xs;
    char* wlb = (char*)wl;

    // ---- stage x chunk for unit u: 3 glds/wave (incl. dummies), pure async ----
    auto stage_x = [&](int u, int chunk) {
        const int b  = u >> 8;
        const int tile = u & 255;
        const int tw = (tile & 7) * 32;
        const int th = (tile >> 3) * 8;
        #pragma unroll
        for (int q = 0; q < 3; ++q) {
            int i  = wv * 3 + q;        // 0..23
            int pi = i * 16 + pil;
            int r   = pi / 34;
            int lcv = pi - r * 34;
            int gr = th - 1 + r;
            int gc = tw - 1 + lcv;
            bool inb = (pi < 340) & ((unsigned)gr < 256u) & ((unsigned)gc < 256u);
            unsigned off = inb
                ? (unsigned)(XT_OFF + (unsigned)((b * HWSZ) + (gr << 8) + gc) * 128u + slot * 16)
                : (unsigned)(ZP_OFF + slot * 16);
            const char* g = ws + off + chunk * 64;
            unsigned short* l = xs + chunk * 12288 + i * 512;
            __builtin_amdgcn_global_load_lds(
                (const __attribute__((address_space(1))) void*)(const void*)g,
                (__attribute__((address_space(3))) void*)(void*)l, 16, 0, 0);
        }
    };

    // ---- full weight stage (once): 9 glds/wave ----
    auto stage_wl = [&]() {
        const unsigned short* base = (const unsigned short*)(ws + WSW_OFF);
        #pragma unroll
        for (int q = 0; q < 9; ++q) {
            int i = wv + 8 * q;         // 0..71
            const unsigned short* g = base + i * 512 + lane * 8;
            unsigned short* l = wl + i * 512;
            __builtin_amdgcn_global_load_lds(
                (const __attribute__((address_space(1))) void*)(const void*)g,
                (__attribute__((address_space(3))) void*)(void*)l, 16, 0, 0);
        }
    };

    f32x4 acc[4][2];

    auto do_mfma = [&](int chunk) {
        #pragma unroll
        for (int kh = 0; kh < 3; ++kh) {
            #pragma unroll
            for (int kw = 0; kw < 3; ++kw) {
                const int kpos = kh * 3 + kw;
                bf16x8 bfrag[2];
                #pragma unroll
                for (int j = 0; j < 2; ++j) {
                    int co = coh * 32 + j * 16 + l15;
                    int sl = l4 ^ (((co & 31) >> 1) & 3);
                    bfrag[j] = *(const bf16x8*)(wlb + chunk * 36864 + (kpos * 64 + co) * 64 + (sl << 4));
                }
                #pragma unroll
                for (int f = 0; f < 4; ++f) {
                    int fr = f >> 1, wh = f & 1;
                    int lc = wh * 16 + l15 + kw;
                    int r  = rg * 2 + fr + kh;
                    int s  = (lc >> 1) & 3;
                    bf16x8 afrag = *(const bf16x8*)(xsb + chunk * 24576 + (r * 34 + lc) * 64 + ((l4 ^ s) << 4));
                    #pragma unroll
                    for (int j = 0; j < 2; ++j)
                        acc[f][j] = __builtin_amdgcn_mfma_f32_16x16x32_bf16(
                            afrag, bfrag[j], acc[f][j], 0, 0, 0);
                }
            }
        }
    };

    // ---- prologue ----
    stage_wl();                 // 9 vm-ops/wave
    stage_x(bk * 8, 0);         // 3 vm-ops/wave

    float bv[2];
    #pragma unroll
    for (int j = 0; j < 2; ++j) bv[j] = bias[coh * 32 + j * 16 + l15];

    for (int it = 0; it < 8; ++it) {
        const int u  = bk * 8 + it;
        const int b  = u >> 8;
        const int tile = u & 255;
        const int tw = (tile & 7) * 32;
        const int th = (tile >> 3) * 8;

        #pragma unroll
        for (int f = 0; f < 4; ++f)
            #pragma unroll
            for (int j = 0; j < 2; ++j)
                acc[f][j] = (f32x4){0.f, 0.f, 0.f, 0.f};

        // ---- step A: issue mask (4) + stage chunk1 (3); wait chunk0 ready ----
        const int* mb = mask + (size_t)b * HWSZ;
        int4 mv[2][2];
        #pragma unroll
        for (int fr = 0; fr < 2; ++fr) {
            int h   = th + rg * 2 + fr;
            int wq0 = tw + l4 * 4;
            mv[fr][0] = *(const int4*)(mb + h * 256 + wq0);
            mv[fr][1] = *(const int4*)(mb + h * 256 + wq0 + 16);
        }
        stage_x(u, 1);
        VMCNT(7);               // leaves mask(4)+stage_c1(3): chunk0 + prior stores done
        BARRIER();
        do_mfma(0);
        BARRIER();

        // ---- step B: issue next tile's chunk0 (3); wait chunk1 + mask ready ----
        {
            int un = (u + 1 < 2048) ? (u + 1) : 0;
            stage_x(un, 0);
        }
        VMCNT(3);               // leaves stage_c0(next): chunk1 + mask done
        BARRIER();
        do_mfma(1);
        BARRIER();

        // ---- epilogue: bias + mask, 8 stores/wave ----
        #pragma unroll
        for (int fr = 0; fr < 2; ++fr) {
            int h   = th + rg * 2 + fr;
            int wq0 = tw + l4 * 4;
            float m00 = (float)mv[fr][0].x, m01 = (float)mv[fr][0].y;
            float m02 = (float)mv[fr][0].z, m03 = (float)mv[fr][0].w;
            float m10 = (float)mv[fr][1].x, m11 = (float)mv[fr][1].y;
            float m12 = (float)mv[fr][1].z, m13 = (float)mv[fr][1].w;
            #pragma unroll
            for (int j = 0; j < 2; ++j) {
                int co = coh * 32 + j * 16 + l15;
                float* obase = out + (((size_t)(b * 64 + co)) << 16) + h * 256;
                f32x4 a0 = acc[fr * 2 + 0][j];
                f32x4 a1 = acc[fr * 2 + 1][j];
                float4 o0, o1;
                o0.x = (a0.x + bv[j]) * m00;
                o0.y = (a0.y + bv[j]) * m01;
                o0.z = (a0.z + bv[j]) * m02;
                o0.w = (a0.w + bv[j]) * m03;
                o1.x = (a1.x + bv[j]) * m10;
                o1.y = (a1.y + bv[j]) * m11;
                o1.z = (a1.z + bv[j]) * m12;
                o1.w = (a1.w + bv[j]) * m13;
                *(float4*)(obase + wq0) = o0;
                *(float4*)(obase + wq0 + 16) = o1;
            }
        }
    }
}

extern "C" void kernel_launch(void* const* d_in, const int* in_sizes, int n_in,
                              void* d_out, int out_size, void* d_ws, size_t ws_size,
                              hipStream_t stream) {
    const float* x    = (const float*)d_in[0];
    const int*   mask = (const int*)d_in[1];
    const float* wgt  = (const float*)d_in[2];
    const float* bias = (const float*)d_in[3];
    float* out = (float*)d_out;
    char* ws = (char*)d_ws;     // uses XT_OFF + 64 MiB of ws

    wcvt<<<dim3(144), dim3(256), 0, stream>>>(wgt, ws);
    xcvt<<<dim3(512, 8), dim3(256), 0, stream>>>(x, ws);
    maskconv_mfma<<<dim3(256), dim3(512), 0, stream>>>(ws, mask, bias, out);
}